// Round 17
// baseline (530.590 us; speedup 1.0000x reference)
//
#include <hip/hip_runtime.h>

typedef __bf16 bf16_t;
typedef __bf16 bf16x8 __attribute__((ext_vector_type(8)));
typedef __bf16 bf16x4 __attribute__((ext_vector_type(4)));
typedef float f32x4 __attribute__((ext_vector_type(4)));
typedef float f32x16 __attribute__((ext_vector_type(16)));
typedef unsigned u32x4 __attribute__((ext_vector_type(4)));

#define NTOK 1568
#define CDIM 512
#define BATCH 4
#define MROWS (BATCH*NTOK)  // 6272
#define RSQ1PEPS 0.9999950000374997f
#define CEXP 0.1803368801111204f    // 0.125 * log2(e), folded into q-projection

__device__ __forceinline__ float fexp2(float x) {
  float r;
  asm("v_exp_f32 %0, %1" : "=v"(r) : "v"(x));
  return r;
}

__device__ __forceinline__ void glds16(const bf16_t* src, bf16_t* dst) {
  __builtin_amdgcn_global_load_lds(
      (const __attribute__((address_space(1))) unsigned*)src,
      (__attribute__((address_space(3))) unsigned*)dst, 16, 0, 0);
}

// ---------------- cast all weights f32 -> bf16 (one launch) ----------------
struct CastArgs { const float* s[20]; };
__global__ __launch_bounds__(256) void cast_kernel(CastArgs ca, bf16_t* __restrict__ out) {
  int idx = blockIdx.x * 256 + threadIdx.x;
  int m = idx >> 16;
  const float4* sp = (const float4*)ca.s[m];
  float4 v = sp[idx & 65535];
  bf16x4 o;
  o[0] = (bf16_t)v.x; o[1] = (bf16_t)v.y; o[2] = (bf16_t)v.z; o[3] = (bf16_t)v.w;
  *(bf16x4*)(out + (size_t)idx * 4) = o;
}

// ---------------- tokenize both inputs: x[b][c][s] -> t[b][s][c] ----------------
struct TokArgs { const float* x[2]; float* tf[2]; bf16_t* tb[2]; };
__global__ __launch_bounds__(256) void tok_kernel(TokArgs ta) {
  __shared__ float tile[32][33];
  int z = blockIdx.z, sel = z >> 2, b = z & 3;
  int c0 = blockIdx.y * 32, s0 = blockIdx.x * 32;
  int tx = threadIdx.x, ty = threadIdx.y;
  const float* xp = ta.x[sel] + (size_t)b * CDIM * NTOK;
  for (int r = 0; r < 32; r += 8)
    tile[ty + r][tx] = xp[(size_t)(c0 + ty + r) * NTOK + s0 + tx];
  __syncthreads();
  float* tfp = ta.tf[sel] + (size_t)b * NTOK * CDIM;
  bf16_t* tbp = ta.tb[sel] + (size_t)b * NTOK * CDIM;
  for (int r = 0; r < 32; r += 8) {
    float v = tile[tx][ty + r];
    size_t idx = (size_t)(s0 + ty + r) * CDIM + c0 + tx;
    tfp[idx] = v;
    tbp[idx] = (bf16_t)v;
  }
}

// ---------------- LayerNorm both streams: f32 in -> bf16 out ----------------
__global__ __launch_bounds__(64) void ln_kernel(
    const float* __restrict__ t1, const float* __restrict__ t2,
    const float* __restrict__ g1, const float* __restrict__ b1,
    const float* __restrict__ g2, const float* __restrict__ b2,
    bf16_t* __restrict__ o1, bf16_t* __restrict__ o2) {
  int row = blockIdx.x;
  const float* t; const float* g; const float* bt; bf16_t* out;
  if (row < MROWS) { t = t1; g = g1; bt = b1; out = o1; }
  else { row -= MROWS; t = t2; g = g2; bt = b2; out = o2; }
  int l = threadIdx.x;
  const float* x = t + (size_t)row * CDIM;
  float4 v0 = ((const float4*)x)[l];
  float4 v1 = ((const float4*)x)[l + 64];
  float s = v0.x + v0.y + v0.z + v0.w + v1.x + v1.y + v1.z + v1.w;
  float sq = v0.x*v0.x + v0.y*v0.y + v0.z*v0.z + v0.w*v0.w
           + v1.x*v1.x + v1.y*v1.y + v1.z*v1.z + v1.w*v1.w;
  for (int m = 1; m < 64; m <<= 1) { s += __shfl_xor(s, m); sq += __shfl_xor(sq, m); }
  float mean = s * (1.f / 512.f);
  float var = sq * (1.f / 512.f) - mean * mean;
  float rs = rsqrtf(var + 1e-5f);
  float4 g0 = ((const float4*)g)[l], g1v = ((const float4*)g)[l + 64];
  float4 b0 = ((const float4*)bt)[l], b1v = ((const float4*)bt)[l + 64];
  bf16x4 o0, o1v;
  o0[0] = (bf16_t)((v0.x - mean) * rs * g0.x + b0.x);
  o0[1] = (bf16_t)((v0.y - mean) * rs * g0.y + b0.y);
  o0[2] = (bf16_t)((v0.z - mean) * rs * g0.z + b0.z);
  o0[3] = (bf16_t)((v0.w - mean) * rs * g0.w + b0.w);
  o1v[0] = (bf16_t)((v1.x - mean) * rs * g1v.x + b1v.x);
  o1v[1] = (bf16_t)((v1.y - mean) * rs * g1v.y + b1v.y);
  o1v[2] = (bf16_t)((v1.z - mean) * rs * g1v.z + b1v.z);
  o1v[3] = (bf16_t)((v1.w - mean) * rs * g1v.w + b1v.w);
  *(bf16x4*)(out + (size_t)row * CDIM + l * 4) = o0;
  *(bf16x4*)(out + (size_t)row * CDIM + 256 + l * 4) = o1v;
}

// ---------------- shared GEMM core: D = A[M][512] * B[N][512]^T ----------------
template<int MODE>
__device__ __forceinline__ void gemm_core(
    bf16_t (* __restrict__ As)[40], bf16_t (* __restrict__ Bs)[40],
    const bf16_t* __restrict__ A, const bf16_t* __restrict__ Bp,
    const float* __restrict__ bias, const float* __restrict__ bng,
    const float* __restrict__ bnb, bf16_t* __restrict__ outb,
    float* __restrict__ outf, int m0, int n0, int Nvalid, float scl) {
  int tid = threadIdx.x;
  int w = tid >> 6, l = tid & 63, lr = l & 15, kg = l >> 4;
  int wm = (w >> 1) * 64, wn = (w & 1) * 64;
  f32x4 acc[4][4];
  for (int i = 0; i < 4; i++)
    for (int j = 0; j < 4; j++)
      acc[i][j] = f32x4{0.f, 0.f, 0.f, 0.f};
  int srow = tid >> 1;
  int soff = (tid & 1) * 16;
  int brow = n0 + srow;
  if (MODE != 0 && brow >= Nvalid) brow = Nvalid - 1;
  const bf16_t* aq = A + (size_t)(m0 + srow) * CDIM + soff;
  const bf16_t* bq = Bp + (size_t)brow * CDIM + soff;
  for (int kk = 0; kk < 16; kk++) {
    __syncthreads();
    bf16x8 a0 = *(const bf16x8*)(aq);
    bf16x8 a1 = *(const bf16x8*)(aq + 8);
    bf16x8 b0 = *(const bf16x8*)(bq);
    bf16x8 b1 = *(const bf16x8*)(bq + 8);
    aq += 32; bq += 32;
    *(bf16x8*)&As[srow][soff] = a0;
    *(bf16x8*)&As[srow][soff + 8] = a1;
    *(bf16x8*)&Bs[srow][soff] = b0;
    *(bf16x8*)&Bs[srow][soff + 8] = b1;
    __syncthreads();
    bf16x8 af[4], bfr[4];
    for (int i = 0; i < 4; i++) af[i] = *(const bf16x8*)&As[wm + i * 16 + lr][kg * 8];
    for (int j = 0; j < 4; j++) bfr[j] = *(const bf16x8*)&Bs[wn + j * 16 + lr][kg * 8];
    for (int i = 0; i < 4; i++)
      for (int j = 0; j < 4; j++)
        acc[i][j] = __builtin_amdgcn_mfma_f32_16x16x32_bf16(af[i], bfr[j], acc[i][j], 0, 0, 0);
  }
  for (int i = 0; i < 4; i++)
    for (int j = 0; j < 4; j++) {
      int rbase = m0 + wm + i * 16 + kg * 4;
      int col = n0 + wn + j * 16 + lr;
      for (int r = 0; r < 4; r++) {
        int row = rbase + r;
        float v = acc[i][j][r];
        if (MODE == 0) {
          v = (v + bias[col]) * scl;
          outb[(size_t)row * CDIM + col] = (bf16_t)v;
        } else if (MODE == 1) {
          v += bias[row];
          v = v > 0.f ? v : 0.f;
          v *= RSQ1PEPS;
          v = v * bng[row] + bnb[row];
          if (col < Nvalid) outf[(size_t)row * NTOK + col] = v;
        } else {
          v += bias[row];
          if (col < Nvalid) outb[(size_t)row * NTOK + col] = (bf16_t)v;
        }
      }
    }
}

// ---------------- fused per-stage projections ----------------
struct ProjArgs {
  const bf16_t* A0[4]; const bf16_t* W0[4]; const float* b0[4]; bf16_t* o0[4];
  float scl0[4];
  const bf16_t* W2[2]; const bf16_t* B2[2]; const float* b2[2]; bf16_t* o2[2];
};
__global__ __launch_bounds__(256) void proj_kernel(ProjArgs p) {
  __shared__ bf16_t As[128][40];
  __shared__ bf16_t Bs[128][40];
  int id = blockIdx.x;
  if (id < 784) {
    int set = id / 196, rem = id % 196;
    int n0 = (rem & 3) * 128, m0 = (rem >> 2) * 128;
    gemm_core<0>(As, Bs, p.A0[set], p.W0[set], p.b0[set], nullptr, nullptr,
                 p.o0[set], nullptr, m0, n0, 512, p.scl0[set]);
  } else {
    int j = id - 784;
    int unit = j / 52;
    int which = unit >> 2, bat = unit & 3;
    int rem = j % 52;
    int n0 = (rem % 13) * 128, m0 = (rem / 13) * 128;
    gemm_core<2>(As, Bs, p.W2[which], p.B2[which] + (size_t)bat * NTOK * CDIM,
                 p.b2[which], nullptr, nullptr,
                 p.o2[which] + (size_t)bat * CDIM * NTOK, nullptr, m0, n0, NTOK, 1.f);
  }
}

// ---------------- fused out-heads (MODE 1) ----------------
__global__ __launch_bounds__(256) void head_kernel(
    const bf16_t* __restrict__ W1, const bf16_t* __restrict__ W2,
    const bf16_t* __restrict__ t1b, const bf16_t* __restrict__ t2b,
    const float* __restrict__ b1, const float* __restrict__ b2,
    const float* __restrict__ bng1, const float* __restrict__ bnb1,
    const float* __restrict__ bng2, const float* __restrict__ bnb2,
    float* __restrict__ out) {
  __shared__ bf16_t As[128][40];
  __shared__ bf16_t Bs[128][40];
  int z = blockIdx.z;
  int which = z >> 2, bat = z & 3;
  const bf16_t* A = which ? W2 : W1;
  const bf16_t* Bp = (which ? t2b : t1b) + (size_t)bat * NTOK * CDIM;
  const float* bias = which ? b2 : b1;
  const float* bng = which ? bng2 : bng1;
  const float* bnb = which ? bnb2 : bnb1;
  float* outf = out + (size_t)which * BATCH * CDIM * NTOK + (size_t)bat * CDIM * NTOK;
  int m0 = blockIdx.y * 128, n0 = blockIdx.x * 128;
  gemm_core<1>(As, Bs, A, Bp, bias, bng, bnb, nullptr, outf, m0, n0, NTOK, 1.f);
}

// ---------------- attention helpers ----------------
__device__ __forceinline__ void build_frags(const float* p, bf16x8& Fa, bf16x8& Fb) {
  unsigned pk[8];
#pragma unroll
  for (int g = 0; g < 8; g++) {
    union { bf16_t hh[2]; unsigned u; } cv;
    cv.hh[0] = (bf16_t)p[2 * g];
    cv.hh[1] = (bf16_t)p[2 * g + 1];
    pk[g] = cv.u;
  }
  asm volatile("v_permlane32_swap_b32 %0, %1" : "+v"(pk[0]), "+v"(pk[2]));
  asm volatile("v_permlane32_swap_b32 %0, %1" : "+v"(pk[1]), "+v"(pk[3]));
  asm volatile("v_permlane32_swap_b32 %0, %1" : "+v"(pk[4]), "+v"(pk[6]));
  asm volatile("v_permlane32_swap_b32 %0, %1" : "+v"(pk[5]), "+v"(pk[7]));
  union { u32x4 u; bf16x8 bv; } A, B;
  A.u[0] = pk[0]; A.u[1] = pk[1]; A.u[2] = pk[2]; A.u[3] = pk[3];
  B.u[0] = pk[4]; B.u[1] = pk[5]; B.u[2] = pk[6]; B.u[3] = pk[7];
  Fa = A.bv; Fb = B.bv;
}

// ---------------- fused attention: 2 q-sets/wave, KVB=32, ring-4, static-max ----------------
struct AttnArgs {
  const bf16_t* q[2]; const bf16_t* k[2]; const bf16_t* v[2];
  float* tf[2]; bf16_t* tb[2];
};

#define STAGE(TN, SL)                                                         \
  {                                                                           \
    int tnS_ = (TN); if (tnS_ > 48) tnS_ = 48;                                \
    glds16(kgl + (size_t)tnS_ * (32 * CDIM), &Ks[SL][wq8][0]);                \
    glds16(vgl + tnS_ * 32, &Vs[SL][wq16][0]);                                \
  }

// QK for both q-sets: K fragments loaded ONCE, reused (q-independent)
#define QK2(SL)                                                               \
  {                                                                           \
    const bf16_t* kr_ = &Ks[SL][lo][0];                                       \
    bf16x8 k0_ = *(const bf16x8*)(kr_ + ((hi * 8) ^ sw3));                    \
    bf16x8 k1_ = *(const bf16x8*)(kr_ + ((16 + hi * 8) ^ sw3));               \
    bf16x8 k2_ = *(const bf16x8*)(kr_ + ((32 + hi * 8) ^ sw3));               \
    bf16x8 k3_ = *(const bf16x8*)(kr_ + ((48 + hi * 8) ^ sw3));               \
    __builtin_amdgcn_s_setprio(1);                                            \
    saA = __builtin_amdgcn_mfma_f32_32x32x16_bf16(k0_, qfA[0], z, 0, 0, 0);   \
    saB = __builtin_amdgcn_mfma_f32_32x32x16_bf16(k0_, qfB[0], z, 0, 0, 0);   \
    saA = __builtin_amdgcn_mfma_f32_32x32x16_bf16(k1_, qfA[1], saA, 0, 0, 0); \
    saB = __builtin_amdgcn_mfma_f32_32x32x16_bf16(k1_, qfB[1], saB, 0, 0, 0); \
    saA = __builtin_amdgcn_mfma_f32_32x32x16_bf16(k2_, qfA[2], saA, 0, 0, 0); \
    saB = __builtin_amdgcn_mfma_f32_32x32x16_bf16(k2_, qfB[2], saB, 0, 0, 0); \
    saA = __builtin_amdgcn_mfma_f32_32x32x16_bf16(k3_, qfA[3], saA, 0, 0, 0); \
    saB = __builtin_amdgcn_mfma_f32_32x32x16_bf16(k3_, qfB[3], saB, 0, 0, 0); \
    __builtin_amdgcn_s_setprio(0);                                            \
  }

// finish both q-sets: V fragments loaded ONCE, reused; ls via ones-MFMA
#define FIN2(SL)                                                              \
  {                                                                           \
    float pa_[16], pb_[16];                                                   \
    _Pragma("unroll")                                                         \
    for (int r_ = 0; r_ < 16; r_++) pa_[r_] = fexp2(saA[r_]);                 \
    _Pragma("unroll")                                                         \
    for (int r_ = 0; r_ < 16; r_++) pb_[r_] = fexp2(saB[r_]);                 \
    bf16x8 FA0_, FA1_, FB0_, FB1_;                                            \
    build_frags(pa_, FA0_, FA1_);                                             \
    build_frags(pb_, FB0_, FB1_);                                             \
    bf16x8 v0_ = *(const bf16x8*)(&Vs[SL][lo][(hi * 8) ^ sw2]);               \
    bf16x8 v1_ = *(const bf16x8*)(&Vs[SL][lo][(16 + hi * 8) ^ sw2]);          \
    bf16x8 v2_ = *(const bf16x8*)(&Vs[SL][32 + lo][(hi * 8) ^ sw2]);          \
    bf16x8 v3_ = *(const bf16x8*)(&Vs[SL][32 + lo][(16 + hi * 8) ^ sw2]);     \
    __builtin_amdgcn_s_setprio(1);                                            \
    lsA = __builtin_amdgcn_mfma_f32_32x32x16_bf16(kone, FA0_, lsA, 0, 0, 0);  \
    lsB = __builtin_amdgcn_mfma_f32_32x32x16_bf16(kone, FB0_, lsB, 0, 0, 0);  \
    lsA = __builtin_amdgcn_mfma_f32_32x32x16_bf16(kone, FA1_, lsA, 0, 0, 0);  \
    lsB = __builtin_amdgcn_mfma_f32_32x32x16_bf16(kone, FB1_, lsB, 0, 0, 0);  \
    otA0 = __builtin_amdgcn_mfma_f32_32x32x16_bf16(v0_, FA0_, otA0, 0, 0, 0); \
    otB0 = __builtin_amdgcn_mfma_f32_32x32x16_bf16(v0_, FB0_, otB0, 0, 0, 0); \
    otA0 = __builtin_amdgcn_mfma_f32_32x32x16_bf16(v1_, FA1_, otA0, 0, 0, 0); \
    otB0 = __builtin_amdgcn_mfma_f32_32x32x16_bf16(v1_, FB1_, otB0, 0, 0, 0); \
    otA1 = __builtin_amdgcn_mfma_f32_32x32x16_bf16(v2_, FA0_, otA1, 0, 0, 0); \
    otB1 = __builtin_amdgcn_mfma_f32_32x32x16_bf16(v2_, FB0_, otB1, 0, 0, 0); \
    otA1 = __builtin_amdgcn_mfma_f32_32x32x16_bf16(v3_, FA1_, otA1, 0, 0, 0); \
    otB1 = __builtin_amdgcn_mfma_f32_32x32x16_bf16(v3_, FB1_, otB1, 0, 0, 0); \
    __builtin_amdgcn_s_setprio(0);                                            \
  }

// one step: stage T+2, compute tile T for both q-sets, retire tile T+1's pair
#define STEPX(T, CUR, SSL)                                                    \
  {                                                                           \
    STAGE((T) + 2, SSL);                                                      \
    QK2(CUR);                                                                 \
    FIN2(CUR);                                                                \
    asm volatile("s_waitcnt vmcnt(2)" ::: "memory");                          \
    __builtin_amdgcn_s_barrier();                                             \
  }

__global__ __launch_bounds__(256) void attn_kernel(AttnArgs aa) {
  __shared__ alignas(16) bf16_t Ks[4][32][64];   // 16KB, 3-bit XOR swizzle
  __shared__ alignas(16) bf16_t Vs[4][64][32];   // 16KB, V^T, 2-bit XOR swizzle
  // XCD-aware decode: all 7 q-blocks of one (s,b,h) on one XCD
  int id = blockIdx.x;
  int xcd = id & 7, sl = id >> 3;          // sl in 0..55
  int g = xcd + ((sl / 7) << 3);           // group 0..63
  int blk = sl % 7;
  int ss = g >> 5, b = (g >> 3) & 3, h = g & 7;
  const bf16_t* qg = aa.q[ss];
  const bf16_t* kgp = aa.k[ss];
  const bf16_t* vtg = aa.v[ss];
  float* tf = aa.tf[ss];
  bf16_t* tb = aa.tb[ss];
  int tid = threadIdx.x, w = tid >> 6, l = tid & 63;
  int lo = l & 31, hi = l >> 5;
  int wq8 = w * 8, wq16 = w * 16;
  int sw3 = (lo & 7) << 3;
  int sw2 = ((lo >> 1) & 3) << 3;
  const size_t kbase = ((size_t)b * NTOK) * CDIM + h * 64;
  const size_t vbase = ((size_t)b * CDIM + h * 64) * NTOK;

  // two q-sets per wave: A = rows blk*256 + w*32 .., B = A + 128
  int q0a = blk * 256 + w * 32;
  int q0b = q0a + 128;
  int qrowA = q0a + lo, qrowB = q0b + lo;
  int qrA = qrowA < NTOK ? qrowA : NTOK - 1;
  int qrB = qrowB < NTOK ? qrowB : NTOK - 1;
  const bf16_t* qpA = qg + kbase + (size_t)qrA * CDIM + hi * 8;
  const bf16_t* qpB = qg + kbase + (size_t)qrB * CDIM + hi * 8;
  bf16x8 qfA[4], qfB[4];
  qfA[0] = *(const bf16x8*)(qpA);
  qfA[1] = *(const bf16x8*)(qpA + 16);
  qfA[2] = *(const bf16x8*)(qpA + 32);
  qfA[3] = *(const bf16x8*)(qpA + 48);
  qfB[0] = *(const bf16x8*)(qpB);
  qfB[1] = *(const bf16x8*)(qpB + 16);
  qfB[2] = *(const bf16x8*)(qpB + 32);
  qfB[3] = *(const bf16x8*)(qpB + 48);
  asm volatile("" : "+v"(qfA[0]), "+v"(qfA[1]), "+v"(qfA[2]), "+v"(qfA[3]));
  asm volatile("" : "+v"(qfB[0]), "+v"(qfB[1]), "+v"(qfB[2]), "+v"(qfB[3]));
  asm volatile("s_waitcnt vmcnt(0)" ::: "memory");   // drain Q: vmcnt counting exact

  // staging source addresses (pre-swizzled col-groups; store perm matches read perm)
  const bf16_t* kgl = kgp + kbase + (size_t)(wq8 + (l >> 3)) * CDIM
                      + (((l & 7) ^ ((l >> 3) & 7)) << 3);
  const bf16_t* vgl = vtg + vbase + (size_t)(wq16 + (l >> 2)) * NTOK
                      + (((l & 3) ^ ((l >> 3) & 3)) << 3);

  bf16x8 kone;
#pragma unroll
  for (int j = 0; j < 8; j++) kone[j] = (bf16_t)1.0f;

  f32x16 otA0, otA1, otB0, otB1, lsA, lsB, z, saA, saB;
#pragma unroll
  for (int r = 0; r < 16; r++) {
    otA0[r] = 0.f; otA1[r] = 0.f; otB0[r] = 0.f; otB1[r] = 0.f;
    lsA[r] = 0.f; lsB[r] = 0.f; z[r] = 0.f;
  }

  // prologue: stage tiles 0,1; retire tile 0's pair (tile 1 stays in flight)
  STAGE(0, 0);
  STAGE(1, 1);
  asm volatile("s_waitcnt vmcnt(2)" ::: "memory");
  __builtin_amdgcn_s_barrier();

  // steady loop: steps 0..47 (12 x 4); step T computes tile T, stages T+2
  for (int t = 0; t < 48; t += 4) {
    STEPX(t + 0, 0, 2);
    STEPX(t + 1, 1, 3);
    STEPX(t + 2, 2, 0);
    STEPX(t + 3, 3, 1);
  }
  // final tile 48 (slot 0), no staging
  QK2(0);
  FIN2(0);
  asm volatile("s_waitcnt vmcnt(0)" ::: "memory");   // drain clamped dup stages

  float* tfb = tf + (size_t)b * NTOK * CDIM + h * 64 + hi * 4;
  bf16_t* tbb = tb + (size_t)b * NTOK * CDIM + h * 64 + hi * 4;
  if (qrowA < NTOK) {
    float inv = 1.f / lsA[0];
    float* tfp = tfb + (size_t)qrowA * CDIM;
    bf16_t* tbp = tbb + (size_t)qrowA * CDIM;
#pragma unroll
    for (int db = 0; db < 2; db++) {
#pragma unroll
      for (int gq = 0; gq < 4; gq++) {
        int doff = db * 32 + gq * 8;
        float4 old = *(float4*)(tfp + doff);
        float4 nv;
        float a0 = (db ? otA1[gq * 4 + 0] : otA0[gq * 4 + 0]) * inv;
        float a1 = (db ? otA1[gq * 4 + 1] : otA0[gq * 4 + 1]) * inv;
        float a2 = (db ? otA1[gq * 4 + 2] : otA0[gq * 4 + 2]) * inv;
        float a3 = (db ? otA1[gq * 4 + 3] : otA0[gq * 4 + 3]) * inv;
        nv.x = old.x + a0; nv.y = old.y + a1; nv.z = old.z + a2; nv.w = old.w + a3;
        *(float4*)(tfp + doff) = nv;
        bf16x4 ob;
        ob[0] = (bf16_t)nv.x; ob[1] = (bf16_t)nv.y;
        ob[2] = (bf16_t)nv.z; ob[3] = (bf16_t)nv.w;
        *(bf16x4*)(tbp + doff) = ob;
      }
    }
  }
  if (qrowB < NTOK) {
    float inv = 1.f / lsB[0];
    float* tfp = tfb + (size_t)qrowB * CDIM;
    bf16_t* tbp = tbb + (size_t)qrowB * CDIM;
#pragma unroll
    for (int db = 0; db < 2; db++) {
#pragma unroll
      for (int gq = 0; gq < 4; gq++) {
        int doff = db * 32 + gq * 8;
        float4 old = *(float4*)(tfp + doff);
        float4 nv;
        float a0 = (db ? otB1[gq * 4 + 0] : otB0[gq * 4 + 0]) * inv;
        float a1 = (db ? otB1[gq * 4 + 1] : otB0[gq * 4 + 1]) * inv;
        float a2 = (db ? otB1[gq * 4 + 2] : otB0[gq * 4 + 2]) * inv;
        float a3 = (db ? otB1[gq * 4 + 3] : otB0[gq * 4 + 3]) * inv;
        nv.x = old.x + a0; nv.y = old.y + a1; nv.z = old.z + a2; nv.w = old.w + a3;
        *(float4*)(tfp + doff) = nv;
        bf16x4 ob;
        ob[0] = (bf16_t)nv.x; ob[1] = (bf16_t)nv.y;
        ob[2] = (bf16_t)nv.z; ob[3] = (bf16_t)nv.w;
        *(bf16x4*)(tbp + doff) = ob;
      }
    }
  }
}

extern "C" void kernel_launch(void* const* d_in, const int* in_sizes, int n_in,
                              void* d_out, int out_size, void* d_ws, size_t ws_size,
                              hipStream_t stream) {
  (void)in_sizes; (void)n_in; (void)out_size; (void)ws_size;
  const float* x1 = (const float*)d_in[0];
  const float* x2 = (const float*)d_in[1];
  const float* Wq1 = (const float*)d_in[2];
  const float* bq1 = (const float*)d_in[3];
  const float* Wk1 = (const float*)d_in[4];
  const float* bk1 = (const float*)d_in[5];
  const float* Wv1 = (const float*)d_in[6];
  const float* bv1 = (const float*)d_in[7];
  const float* ln1_g = (const float*)d_in[8];
  const float* ln1_b = (const float*)d_in[9];
  const float* Wq2 = (const float*)d_in[10];
  const float* bq2 = (const float*)d_in[11];
  const float* Wk2 = (const float*)d_in[12];
  const float* bk2 = (const float*)d_in[13];
  const float* Wv2 = (const float*)d_in[14];
  const float* bv2 = (const float*)d_in[15];
  const float* ln2_g = (const float*)d_in[16];
  const float* ln2_b = (const float*)d_in[17];
  const float* out1_w = (const float*)d_in[18];
  const float* out1_b = (const float*)d_in[19];
  const float* bn1_g = (const float*)d_in[20];
  const float* bn1_b = (const float*)d_in[21];
  const float* out2_w = (const float*)d_in[22];
  const float* out2_b = (const float*)d_in[23];
  const float* bn2_g = (const float*)d_in[24];
  const float* bn2_b = (const float*)d_in[25];

  const size_t WMAT = 512 * 512;
  char* ws = (char*)d_ws;
  bf16_t* wb = (bf16_t*)ws;
  size_t off = 20 * WMAT * sizeof(bf16_t);
  float* t1f = (float*)(ws + off); off += (size_t)MROWS * CDIM * 4;
  float* t2f = (float*)(ws + off); off += (size_t)MROWS * CDIM * 4;
  bf16_t* t1b = (bf16_t*)(ws + off); off += (size_t)MROWS * CDIM * 2;
  bf16_t* t2b = (bf16_t*)(ws + off); off += (size_t)MROWS * CDIM * 2;
  bf16_t* l1b = (bf16_t*)(ws + off); off += (size_t)MROWS * CDIM * 2;
  bf16_t* l2b = (bf16_t*)(ws + off); off += (size_t)MROWS * CDIM * 2;
  bf16_t* q1b = (bf16_t*)(ws + off); off += (size_t)MROWS * CDIM * 2;
  bf16_t* k1b = (bf16_t*)(ws + off); off += (size_t)MROWS * CDIM * 2;
  bf16_t* v1b = (bf16_t*)(ws + off); off += (size_t)MROWS * CDIM * 2;  // V^T [b][512][1568]
  bf16_t* q2b = (bf16_t*)(ws + off); off += (size_t)MROWS * CDIM * 2;
  bf16_t* k2b = (bf16_t*)(ws + off); off += (size_t)MROWS * CDIM * 2;
  bf16_t* v2b = (bf16_t*)(ws + off); off += (size_t)MROWS * CDIM * 2;  // V^T

  CastArgs ca;
  for (int i = 0; i < 3; i++) {
    ca.s[0 + i] = Wq1 + (size_t)i * WMAT;
    ca.s[3 + i] = Wk1 + (size_t)i * WMAT;
    ca.s[6 + i] = Wv1 + (size_t)i * WMAT;
    ca.s[9 + i] = Wq2 + (size_t)i * WMAT;
    ca.s[12 + i] = Wk2 + (size_t)i * WMAT;
    ca.s[15 + i] = Wv2 + (size_t)i * WMAT;
  }
  ca.s[18] = out1_w;
  ca.s[19] = out2_w;
  cast_kernel<<<5120, 256, 0, stream>>>(ca, wb);

  TokArgs ta;
  ta.x[0] = x1; ta.x[1] = x2;
  ta.tf[0] = t1f; ta.tf[1] = t2f;
  ta.tb[0] = t1b; ta.tb[1] = t2b;
  tok_kernel<<<dim3(49, 16, 8), dim3(32, 8), 0, stream>>>(ta);

  AttnArgs aa;
  aa.q[0] = q1b; aa.q[1] = q2b;
  aa.k[0] = k1b; aa.k[1] = k2b;
  aa.v[0] = v1b; aa.v[1] = v2b;
  aa.tf[0] = t1f; aa.tf[1] = t2f;
  aa.tb[0] = t1b; aa.tb[1] = t2b;

  for (int i = 0; i < 3; i++) {
    ln_kernel<<<2 * MROWS, 64, 0, stream>>>(t1f, t2f,
        ln1_g + i * 512, ln1_b + i * 512, ln2_g + i * 512, ln2_b + i * 512,
        l1b, l2b);
    ProjArgs pa;
    pa.A0[0] = l1b; pa.W0[0] = wb + (0 + i) * WMAT; pa.b0[0] = bq1 + i * 512; pa.o0[0] = q1b;
    pa.A0[1] = t2b; pa.W0[1] = wb + (3 + i) * WMAT; pa.b0[1] = bk1 + i * 512; pa.o0[1] = k1b;
    pa.A0[2] = l2b; pa.W0[2] = wb + (9 + i) * WMAT; pa.b0[2] = bq2 + i * 512; pa.o0[2] = q2b;
    pa.A0[3] = t1b; pa.W0[3] = wb + (12 + i) * WMAT; pa.b0[3] = bk2 + i * 512; pa.o0[3] = k2b;
    pa.scl0[0] = CEXP; pa.scl0[1] = 1.f; pa.scl0[2] = CEXP; pa.scl0[3] = 1.f;
    pa.W2[0] = wb + (6 + i) * WMAT; pa.B2[0] = t2b; pa.b2[0] = bv1 + i * 512; pa.o2[0] = v1b;
    pa.W2[1] = wb + (15 + i) * WMAT; pa.B2[1] = t1b; pa.b2[1] = bv2 + i * 512; pa.o2[1] = v2b;
    proj_kernel<<<1200, 256, 0, stream>>>(pa);
    attn_kernel<<<448, 256, 0, stream>>>(aa);
  }

  float* out = (float*)d_out;
  head_kernel<<<dim3(13, 4, 8), 256, 0, stream>>>(
      wb + 18 * WMAT, wb + 19 * WMAT, t1b, t2b,
      out1_b, out2_b, bn1_g, bn1_b, bn2_g, bn2_b, out);
}

// Round 18
// 409.258 us; speedup vs baseline: 1.2965x; 1.2965x over previous
//
#include <hip/hip_runtime.h>

typedef __bf16 bf16_t;
typedef __bf16 bf16x8 __attribute__((ext_vector_type(8)));
typedef __bf16 bf16x4 __attribute__((ext_vector_type(4)));
typedef float f32x4 __attribute__((ext_vector_type(4)));
typedef float f32x16 __attribute__((ext_vector_type(16)));
typedef unsigned u32x4 __attribute__((ext_vector_type(4)));

#define NTOK 1568
#define CDIM 512
#define BATCH 4
#define MROWS (BATCH*NTOK)  // 6272
#define RSQ1PEPS 0.9999950000374997f
#define CEXP 0.1803368801111204f    // 0.125 * log2(e), folded into q-projection

__device__ __forceinline__ float fexp2(float x) {
  float r;
  asm("v_exp_f32 %0, %1" : "=v"(r) : "v"(x));
  return r;
}

__device__ __forceinline__ void glds16(const bf16_t* src, bf16_t* dst) {
  __builtin_amdgcn_global_load_lds(
      (const __attribute__((address_space(1))) unsigned*)src,
      (__attribute__((address_space(3))) unsigned*)dst, 16, 0, 0);
}

// ---------------- cast all weights f32 -> bf16 (one launch) ----------------
struct CastArgs { const float* s[20]; };
__global__ __launch_bounds__(256) void cast_kernel(CastArgs ca, bf16_t* __restrict__ out) {
  int idx = blockIdx.x * 256 + threadIdx.x;
  int m = idx >> 16;
  const float4* sp = (const float4*)ca.s[m];
  float4 v = sp[idx & 65535];
  bf16x4 o;
  o[0] = (bf16_t)v.x; o[1] = (bf16_t)v.y; o[2] = (bf16_t)v.z; o[3] = (bf16_t)v.w;
  *(bf16x4*)(out + (size_t)idx * 4) = o;
}

// ---------------- tokenize both inputs: x[b][c][s] -> t[b][s][c] ----------------
struct TokArgs { const float* x[2]; float* tf[2]; bf16_t* tb[2]; };
__global__ __launch_bounds__(256) void tok_kernel(TokArgs ta) {
  __shared__ float tile[32][33];
  int z = blockIdx.z, sel = z >> 2, b = z & 3;
  int c0 = blockIdx.y * 32, s0 = blockIdx.x * 32;
  int tx = threadIdx.x, ty = threadIdx.y;
  const float* xp = ta.x[sel] + (size_t)b * CDIM * NTOK;
  for (int r = 0; r < 32; r += 8)
    tile[ty + r][tx] = xp[(size_t)(c0 + ty + r) * NTOK + s0 + tx];
  __syncthreads();
  float* tfp = ta.tf[sel] + (size_t)b * NTOK * CDIM;
  bf16_t* tbp = ta.tb[sel] + (size_t)b * NTOK * CDIM;
  for (int r = 0; r < 32; r += 8) {
    float v = tile[tx][ty + r];
    size_t idx = (size_t)(s0 + ty + r) * CDIM + c0 + tx;
    tfp[idx] = v;
    tbp[idx] = (bf16_t)v;
  }
}

// ---------------- LayerNorm both streams: f32 in -> bf16 out ----------------
__global__ __launch_bounds__(64) void ln_kernel(
    const float* __restrict__ t1, const float* __restrict__ t2,
    const float* __restrict__ g1, const float* __restrict__ b1,
    const float* __restrict__ g2, const float* __restrict__ b2,
    bf16_t* __restrict__ o1, bf16_t* __restrict__ o2) {
  int row = blockIdx.x;
  const float* t; const float* g; const float* bt; bf16_t* out;
  if (row < MROWS) { t = t1; g = g1; bt = b1; out = o1; }
  else { row -= MROWS; t = t2; g = g2; bt = b2; out = o2; }
  int l = threadIdx.x;
  const float* x = t + (size_t)row * CDIM;
  float4 v0 = ((const float4*)x)[l];
  float4 v1 = ((const float4*)x)[l + 64];
  float s = v0.x + v0.y + v0.z + v0.w + v1.x + v1.y + v1.z + v1.w;
  float sq = v0.x*v0.x + v0.y*v0.y + v0.z*v0.z + v0.w*v0.w
           + v1.x*v1.x + v1.y*v1.y + v1.z*v1.z + v1.w*v1.w;
  for (int m = 1; m < 64; m <<= 1) { s += __shfl_xor(s, m); sq += __shfl_xor(sq, m); }
  float mean = s * (1.f / 512.f);
  float var = sq * (1.f / 512.f) - mean * mean;
  float rs = rsqrtf(var + 1e-5f);
  float4 g0 = ((const float4*)g)[l], g1v = ((const float4*)g)[l + 64];
  float4 b0 = ((const float4*)bt)[l], b1v = ((const float4*)bt)[l + 64];
  bf16x4 o0, o1v;
  o0[0] = (bf16_t)((v0.x - mean) * rs * g0.x + b0.x);
  o0[1] = (bf16_t)((v0.y - mean) * rs * g0.y + b0.y);
  o0[2] = (bf16_t)((v0.z - mean) * rs * g0.z + b0.z);
  o0[3] = (bf16_t)((v0.w - mean) * rs * g0.w + b0.w);
  o1v[0] = (bf16_t)((v1.x - mean) * rs * g1v.x + b1v.x);
  o1v[1] = (bf16_t)((v1.y - mean) * rs * g1v.y + b1v.y);
  o1v[2] = (bf16_t)((v1.z - mean) * rs * g1v.z + b1v.z);
  o1v[3] = (bf16_t)((v1.w - mean) * rs * g1v.w + b1v.w);
  *(bf16x4*)(out + (size_t)row * CDIM + l * 4) = o0;
  *(bf16x4*)(out + (size_t)row * CDIM + 256 + l * 4) = o1v;
}

// ---------------- shared GEMM core: D = A[M][512] * B[N][512]^T ----------------
template<int MODE>
__device__ __forceinline__ void gemm_core(
    bf16_t (* __restrict__ As)[40], bf16_t (* __restrict__ Bs)[40],
    const bf16_t* __restrict__ A, const bf16_t* __restrict__ Bp,
    const float* __restrict__ bias, const float* __restrict__ bng,
    const float* __restrict__ bnb, bf16_t* __restrict__ outb,
    float* __restrict__ outf, int m0, int n0, int Nvalid, float scl) {
  int tid = threadIdx.x;
  int w = tid >> 6, l = tid & 63, lr = l & 15, kg = l >> 4;
  int wm = (w >> 1) * 64, wn = (w & 1) * 64;
  f32x4 acc[4][4];
  for (int i = 0; i < 4; i++)
    for (int j = 0; j < 4; j++)
      acc[i][j] = f32x4{0.f, 0.f, 0.f, 0.f};
  int srow = tid >> 1;
  int soff = (tid & 1) * 16;
  int brow = n0 + srow;
  if (MODE != 0 && brow >= Nvalid) brow = Nvalid - 1;
  const bf16_t* aq = A + (size_t)(m0 + srow) * CDIM + soff;
  const bf16_t* bq = Bp + (size_t)brow * CDIM + soff;
  for (int kk = 0; kk < 16; kk++) {
    __syncthreads();
    bf16x8 a0 = *(const bf16x8*)(aq);
    bf16x8 a1 = *(const bf16x8*)(aq + 8);
    bf16x8 b0 = *(const bf16x8*)(bq);
    bf16x8 b1 = *(const bf16x8*)(bq + 8);
    aq += 32; bq += 32;
    *(bf16x8*)&As[srow][soff] = a0;
    *(bf16x8*)&As[srow][soff + 8] = a1;
    *(bf16x8*)&Bs[srow][soff] = b0;
    *(bf16x8*)&Bs[srow][soff + 8] = b1;
    __syncthreads();
    bf16x8 af[4], bfr[4];
    for (int i = 0; i < 4; i++) af[i] = *(const bf16x8*)&As[wm + i * 16 + lr][kg * 8];
    for (int j = 0; j < 4; j++) bfr[j] = *(const bf16x8*)&Bs[wn + j * 16 + lr][kg * 8];
    for (int i = 0; i < 4; i++)
      for (int j = 0; j < 4; j++)
        acc[i][j] = __builtin_amdgcn_mfma_f32_16x16x32_bf16(af[i], bfr[j], acc[i][j], 0, 0, 0);
  }
  for (int i = 0; i < 4; i++)
    for (int j = 0; j < 4; j++) {
      int rbase = m0 + wm + i * 16 + kg * 4;
      int col = n0 + wn + j * 16 + lr;
      for (int r = 0; r < 4; r++) {
        int row = rbase + r;
        float v = acc[i][j][r];
        if (MODE == 0) {
          v = (v + bias[col]) * scl;
          outb[(size_t)row * CDIM + col] = (bf16_t)v;
        } else if (MODE == 1) {
          v += bias[row];
          v = v > 0.f ? v : 0.f;
          v *= RSQ1PEPS;
          v = v * bng[row] + bnb[row];
          if (col < Nvalid) outf[(size_t)row * NTOK + col] = v;
        } else {
          v += bias[row];
          if (col < Nvalid) outb[(size_t)row * NTOK + col] = (bf16_t)v;
        }
      }
    }
}

// ---------------- fused per-stage projections ----------------
struct ProjArgs {
  const bf16_t* A0[4]; const bf16_t* W0[4]; const float* b0[4]; bf16_t* o0[4];
  float scl0[4];
  const bf16_t* W2[2]; const bf16_t* B2[2]; const float* b2[2]; bf16_t* o2[2];
};
__global__ __launch_bounds__(256) void proj_kernel(ProjArgs p) {
  __shared__ bf16_t As[128][40];
  __shared__ bf16_t Bs[128][40];
  int id = blockIdx.x;
  if (id < 784) {
    int set = id / 196, rem = id % 196;
    int n0 = (rem & 3) * 128, m0 = (rem >> 2) * 128;
    gemm_core<0>(As, Bs, p.A0[set], p.W0[set], p.b0[set], nullptr, nullptr,
                 p.o0[set], nullptr, m0, n0, 512, p.scl0[set]);
  } else {
    int j = id - 784;
    int unit = j / 52;
    int which = unit >> 2, bat = unit & 3;
    int rem = j % 52;
    int n0 = (rem % 13) * 128, m0 = (rem / 13) * 128;
    gemm_core<2>(As, Bs, p.W2[which], p.B2[which] + (size_t)bat * NTOK * CDIM,
                 p.b2[which], nullptr, nullptr,
                 p.o2[which] + (size_t)bat * CDIM * NTOK, nullptr, m0, n0, NTOK, 1.f);
  }
}

// ---------------- fused out-heads (MODE 1) ----------------
__global__ __launch_bounds__(256) void head_kernel(
    const bf16_t* __restrict__ W1, const bf16_t* __restrict__ W2,
    const bf16_t* __restrict__ t1b, const bf16_t* __restrict__ t2b,
    const float* __restrict__ b1, const float* __restrict__ b2,
    const float* __restrict__ bng1, const float* __restrict__ bnb1,
    const float* __restrict__ bng2, const float* __restrict__ bnb2,
    float* __restrict__ out) {
  __shared__ bf16_t As[128][40];
  __shared__ bf16_t Bs[128][40];
  int z = blockIdx.z;
  int which = z >> 2, bat = z & 3;
  const bf16_t* A = which ? W2 : W1;
  const bf16_t* Bp = (which ? t2b : t1b) + (size_t)bat * NTOK * CDIM;
  const float* bias = which ? b2 : b1;
  const float* bng = which ? bng2 : bng1;
  const float* bnb = which ? bnb2 : bnb1;
  float* outf = out + (size_t)which * BATCH * CDIM * NTOK + (size_t)bat * CDIM * NTOK;
  int m0 = blockIdx.y * 128, n0 = blockIdx.x * 128;
  gemm_core<1>(As, Bs, A, Bp, bias, bng, bnb, nullptr, outf, m0, n0, NTOK, 1.f);
}

// ---------------- attention helpers ----------------
__device__ __forceinline__ void build_frags(const float* p, bf16x8& Fa, bf16x8& Fb) {
  unsigned pk[8];
#pragma unroll
  for (int g = 0; g < 8; g++) {
    union { bf16_t hh[2]; unsigned u; } cv;
    cv.hh[0] = (bf16_t)p[2 * g];
    cv.hh[1] = (bf16_t)p[2 * g + 1];
    pk[g] = cv.u;
  }
  asm volatile("v_permlane32_swap_b32 %0, %1" : "+v"(pk[0]), "+v"(pk[2]));
  asm volatile("v_permlane32_swap_b32 %0, %1" : "+v"(pk[1]), "+v"(pk[3]));
  asm volatile("v_permlane32_swap_b32 %0, %1" : "+v"(pk[4]), "+v"(pk[6]));
  asm volatile("v_permlane32_swap_b32 %0, %1" : "+v"(pk[5]), "+v"(pk[7]));
  union { u32x4 u; bf16x8 bv; } A, B;
  A.u[0] = pk[0]; A.u[1] = pk[1]; A.u[2] = pk[2]; A.u[3] = pk[3];
  B.u[0] = pk[4]; B.u[1] = pk[5]; B.u[2] = pk[6]; B.u[3] = pk[7];
  Fa = A.bv; Fb = B.bv;
}

// ---------------- fused attention: 2-wave blocks, KVB=32, ring-4, static-max ----------------
struct AttnArgs {
  const bf16_t* q[2]; const bf16_t* k[2]; const bf16_t* v[2];
  float* tf[2]; bf16_t* tb[2];
};

// 128-thread block: each wave stages half the K rows (2 glds) + half the V rows (2 glds)
#define STAGE(TN, SL)                                                         \
  {                                                                           \
    int tnS_ = (TN); if (tnS_ > 48) tnS_ = 48;                                \
    const bf16_t* kq_ = kgl + (size_t)tnS_ * (32 * CDIM);                     \
    glds16(kq_, &Ks[SL][wq8][0]);                                             \
    glds16(kq_ + (size_t)16 * CDIM, &Ks[SL][16 + wq8][0]);                    \
    const bf16_t* vq_ = vgl + tnS_ * 32;                                      \
    glds16(vq_, &Vs[SL][wq16][0]);                                            \
    glds16(vq_ + (size_t)32 * NTOK, &Vs[SL][32 + wq16][0]);                   \
  }

#define QK(SL, SA)                                                            \
  {                                                                           \
    const bf16_t* kr_ = &Ks[SL][lo][0];                                       \
    __builtin_amdgcn_s_setprio(1);                                            \
    SA = __builtin_amdgcn_mfma_f32_32x32x16_bf16(                             \
        *(const bf16x8*)(kr_ + ((hi * 8) ^ sw3)), qf[0], z, 0, 0, 0);         \
    SA = __builtin_amdgcn_mfma_f32_32x32x16_bf16(                             \
        *(const bf16x8*)(kr_ + ((16 + hi * 8) ^ sw3)), qf[1], SA, 0, 0, 0);   \
    SA = __builtin_amdgcn_mfma_f32_32x32x16_bf16(                             \
        *(const bf16x8*)(kr_ + ((32 + hi * 8) ^ sw3)), qf[2], SA, 0, 0, 0);   \
    SA = __builtin_amdgcn_mfma_f32_32x32x16_bf16(                             \
        *(const bf16x8*)(kr_ + ((48 + hi * 8) ^ sw3)), qf[3], SA, 0, 0, 0);   \
    __builtin_amdgcn_s_setprio(0);                                            \
  }

// static-max finish: p = exp2(SA); denominator via ones-MFMA (matrix pipe)
#define FIN(SA, SL)                                                           \
  {                                                                           \
    float pa_[16];                                                            \
    _Pragma("unroll")                                                         \
    for (int r_ = 0; r_ < 16; r_++) pa_[r_] = fexp2(SA[r_]);                  \
    bf16x8 F0_, F1_;                                                          \
    build_frags(pa_, F0_, F1_);                                               \
    __builtin_amdgcn_s_setprio(1);                                            \
    ls = __builtin_amdgcn_mfma_f32_32x32x16_bf16(kone, F0_, ls, 0, 0, 0);     \
    ls = __builtin_amdgcn_mfma_f32_32x32x16_bf16(kone, F1_, ls, 0, 0, 0);     \
    ot0 = __builtin_amdgcn_mfma_f32_32x32x16_bf16(                            \
        *(const bf16x8*)(&Vs[SL][lo][(hi * 8) ^ sw2]), F0_, ot0, 0, 0, 0);    \
    ot0 = __builtin_amdgcn_mfma_f32_32x32x16_bf16(                            \
        *(const bf16x8*)(&Vs[SL][lo][(16 + hi * 8) ^ sw2]), F1_, ot0, 0, 0, 0);\
    ot1 = __builtin_amdgcn_mfma_f32_32x32x16_bf16(                            \
        *(const bf16x8*)(&Vs[SL][32 + lo][(hi * 8) ^ sw2]), F0_, ot1, 0, 0, 0);\
    ot1 = __builtin_amdgcn_mfma_f32_32x32x16_bf16(                            \
        *(const bf16x8*)(&Vs[SL][32 + lo][(16 + hi * 8) ^ sw2]), F1_, ot1, 0, 0, 0);\
    __builtin_amdgcn_s_setprio(0);                                            \
  }

// step T: stage T+2 (4 loads), QK(T), FIN(T-1); vmcnt(4) retires tile T+1 whole
#define STEP(T, SACUR, SAPRV, QSL, FSL, SSL)                                  \
  {                                                                           \
    STAGE((T) + 2, SSL);                                                      \
    QK(QSL, SACUR);                                                           \
    FIN(SAPRV, FSL);                                                          \
    asm volatile("s_waitcnt vmcnt(4)" ::: "memory");                          \
    __builtin_amdgcn_s_barrier();                                             \
  }

__global__ __launch_bounds__(128) void attn_kernel(AttnArgs aa) {
  __shared__ alignas(16) bf16_t Ks[4][32][64];   // 16KB, 3-bit XOR swizzle
  __shared__ alignas(16) bf16_t Vs[4][64][32];   // 16KB, V^T, 2-bit XOR swizzle
  // XCD-aware decode: all 25 q-tiles of one (s,b,h) on one XCD
  int id = blockIdx.x;
  int xcd = id & 7, sl = id >> 3;          // sl in 0..199
  int g = xcd + ((sl / 25) << 3);          // group 0..63
  int qt = sl % 25;
  int ss = g >> 5, b = (g >> 3) & 3, h = g & 7;
  const bf16_t* qg = aa.q[ss];
  const bf16_t* kgp = aa.k[ss];
  const bf16_t* vtg = aa.v[ss];
  float* tf = aa.tf[ss];
  bf16_t* tb = aa.tb[ss];
  int tid = threadIdx.x, w = tid >> 6, l = tid & 63;   // 2 waves
  int lo = l & 31, hi = l >> 5;
  int wq8 = w * 8, wq16 = w * 16;
  int sw3 = (lo & 7) << 3;
  int sw2 = ((lo >> 1) & 3) << 3;
  const size_t kbase = ((size_t)b * NTOK) * CDIM + h * 64;
  const size_t vbase = ((size_t)b * CDIM + h * 64) * NTOK;

  int q0 = qt * 64 + w * 32;
  int qrow = q0 + lo;
  int qr = qrow < NTOK ? qrow : NTOK - 1;
  const bf16_t* qp = qg + kbase + (size_t)qr * CDIM + hi * 8;
  bf16x8 qf[4];
  qf[0] = *(const bf16x8*)(qp);
  qf[1] = *(const bf16x8*)(qp + 16);
  qf[2] = *(const bf16x8*)(qp + 32);
  qf[3] = *(const bf16x8*)(qp + 48);
  asm volatile("" : "+v"(qf[0]), "+v"(qf[1]), "+v"(qf[2]), "+v"(qf[3]));
  asm volatile("s_waitcnt vmcnt(0)" ::: "memory");   // drain Q so vmcnt counting is exact

  // staging source addresses (pre-swizzled col-groups; store perm matches read perm)
  // K issue rows: w*8+(l>>3) and +16; col swizzle key (l>>3)&7 invariant under +16.
  // V issue rows: w*16+(l>>2) and +32; swizzle key (l>>3)&3 invariant under +32.
  const bf16_t* kgl = kgp + kbase + (size_t)(wq8 + (l >> 3)) * CDIM
                      + (((l & 7) ^ ((l >> 3) & 7)) << 3);
  const bf16_t* vgl = vtg + vbase + (size_t)(wq16 + (l >> 2)) * NTOK
                      + (((l & 3) ^ ((l >> 3) & 3)) << 3);

  // ones fragment for the denominator MFMA
  bf16x8 kone;
#pragma unroll
  for (int j = 0; j < 8; j++) kone[j] = (bf16_t)1.0f;

  f32x16 ot0, ot1, ls, z, saA, saB;
#pragma unroll
  for (int r = 0; r < 16; r++) { ot0[r] = 0.f; ot1[r] = 0.f; ls[r] = 0.f; z[r] = 0.f; }

  // prologue: stage tiles 0,1,2 (12 loads); vmcnt(4) retires tiles 0 and 1
  STAGE(0, 0);
  STAGE(1, 1);
  STAGE(2, 2);
  asm volatile("s_waitcnt vmcnt(4)" ::: "memory");
  __builtin_amdgcn_s_barrier();
  QK(0, saA);

  // steady loop: steps t=1..48 (12 x 4); step t's vmcnt retires tile t+1 whole
  for (int t = 1; t <= 45; t += 4) {
    STEP(t + 0, saB, saA, 1, 0, 3);
    STEP(t + 1, saA, saB, 2, 1, 0);
    STEP(t + 2, saB, saA, 3, 2, 1);
    STEP(t + 3, saA, saB, 0, 3, 2);
  }
  // finish tile 48 (slot 0)
  FIN(saA, 0);
  asm volatile("s_waitcnt vmcnt(0)" ::: "memory");   // drain clamped dup stages

  if (qrow < NTOK) {
    float inv = 1.f / ls[0];     // all ls rows identical; lane's col = its q
    float* tfp = tf + ((size_t)b * NTOK + qrow) * CDIM + h * 64 + hi * 4;
    bf16_t* tbp = tb + ((size_t)b * NTOK + qrow) * CDIM + h * 64 + hi * 4;
#pragma unroll
    for (int db = 0; db < 2; db++) {
#pragma unroll
      for (int gq = 0; gq < 4; gq++) {
        int doff = db * 32 + gq * 8;
        float4 old = *(float4*)(tfp + doff);
        float4 nv;
        float a0 = (db ? ot1[gq * 4 + 0] : ot0[gq * 4 + 0]) * inv;
        float a1 = (db ? ot1[gq * 4 + 1] : ot0[gq * 4 + 1]) * inv;
        float a2 = (db ? ot1[gq * 4 + 2] : ot0[gq * 4 + 2]) * inv;
        float a3 = (db ? ot1[gq * 4 + 3] : ot0[gq * 4 + 3]) * inv;
        nv.x = old.x + a0; nv.y = old.y + a1; nv.z = old.z + a2; nv.w = old.w + a3;
        *(float4*)(tfp + doff) = nv;
        bf16x4 ob;
        ob[0] = (bf16_t)nv.x; ob[1] = (bf16_t)nv.y;
        ob[2] = (bf16_t)nv.z; ob[3] = (bf16_t)nv.w;
        *(bf16x4*)(tbp + doff) = ob;
      }
    }
  }
}

extern "C" void kernel_launch(void* const* d_in, const int* in_sizes, int n_in,
                              void* d_out, int out_size, void* d_ws, size_t ws_size,
                              hipStream_t stream) {
  (void)in_sizes; (void)n_in; (void)out_size; (void)ws_size;
  const float* x1 = (const float*)d_in[0];
  const float* x2 = (const float*)d_in[1];
  const float* Wq1 = (const float*)d_in[2];
  const float* bq1 = (const float*)d_in[3];
  const float* Wk1 = (const float*)d_in[4];
  const float* bk1 = (const float*)d_in[5];
  const float* Wv1 = (const float*)d_in[6];
  const float* bv1 = (const float*)d_in[7];
  const float* ln1_g = (const float*)d_in[8];
  const float* ln1_b = (const float*)d_in[9];
  const float* Wq2 = (const float*)d_in[10];
  const float* bq2 = (const float*)d_in[11];
  const float* Wk2 = (const float*)d_in[12];
  const float* bk2 = (const float*)d_in[13];
  const float* Wv2 = (const float*)d_in[14];
  const float* bv2 = (const float*)d_in[15];
  const float* ln2_g = (const float*)d_in[16];
  const float* ln2_b = (const float*)d_in[17];
  const float* out1_w = (const float*)d_in[18];
  const float* out1_b = (const float*)d_in[19];
  const float* bn1_g = (const float*)d_in[20];
  const float* bn1_b = (const float*)d_in[21];
  const float* out2_w = (const float*)d_in[22];
  const float* out2_b = (const float*)d_in[23];
  const float* bn2_g = (const float*)d_in[24];
  const float* bn2_b = (const float*)d_in[25];

  const size_t WMAT = 512 * 512;
  char* ws = (char*)d_ws;
  bf16_t* wb = (bf16_t*)ws;
  size_t off = 20 * WMAT * sizeof(bf16_t);
  float* t1f = (float*)(ws + off); off += (size_t)MROWS * CDIM * 4;
  float* t2f = (float*)(ws + off); off += (size_t)MROWS * CDIM * 4;
  bf16_t* t1b = (bf16_t*)(ws + off); off += (size_t)MROWS * CDIM * 2;
  bf16_t* t2b = (bf16_t*)(ws + off); off += (size_t)MROWS * CDIM * 2;
  bf16_t* l1b = (bf16_t*)(ws + off); off += (size_t)MROWS * CDIM * 2;
  bf16_t* l2b = (bf16_t*)(ws + off); off += (size_t)MROWS * CDIM * 2;
  bf16_t* q1b = (bf16_t*)(ws + off); off += (size_t)MROWS * CDIM * 2;
  bf16_t* k1b = (bf16_t*)(ws + off); off += (size_t)MROWS * CDIM * 2;
  bf16_t* v1b = (bf16_t*)(ws + off); off += (size_t)MROWS * CDIM * 2;  // V^T [b][512][1568]
  bf16_t* q2b = (bf16_t*)(ws + off); off += (size_t)MROWS * CDIM * 2;
  bf16_t* k2b = (bf16_t*)(ws + off); off += (size_t)MROWS * CDIM * 2;
  bf16_t* v2b = (bf16_t*)(ws + off); off += (size_t)MROWS * CDIM * 2;  // V^T

  CastArgs ca;
  for (int i = 0; i < 3; i++) {
    ca.s[0 + i] = Wq1 + (size_t)i * WMAT;
    ca.s[3 + i] = Wk1 + (size_t)i * WMAT;
    ca.s[6 + i] = Wv1 + (size_t)i * WMAT;
    ca.s[9 + i] = Wq2 + (size_t)i * WMAT;
    ca.s[12 + i] = Wk2 + (size_t)i * WMAT;
    ca.s[15 + i] = Wv2 + (size_t)i * WMAT;
  }
  ca.s[18] = out1_w;
  ca.s[19] = out2_w;
  cast_kernel<<<5120, 256, 0, stream>>>(ca, wb);

  TokArgs ta;
  ta.x[0] = x1; ta.x[1] = x2;
  ta.tf[0] = t1f; ta.tf[1] = t2f;
  ta.tb[0] = t1b; ta.tb[1] = t2b;
  tok_kernel<<<dim3(49, 16, 8), dim3(32, 8), 0, stream>>>(ta);

  AttnArgs aa;
  aa.q[0] = q1b; aa.q[1] = q2b;
  aa.k[0] = k1b; aa.k[1] = k2b;
  aa.v[0] = v1b; aa.v[1] = v2b;
  aa.tf[0] = t1f; aa.tf[1] = t2f;
  aa.tb[0] = t1b; aa.tb[1] = t2b;

  for (int i = 0; i < 3; i++) {
    ln_kernel<<<2 * MROWS, 64, 0, stream>>>(t1f, t2f,
        ln1_g + i * 512, ln1_b + i * 512, ln2_g + i * 512, ln2_b + i * 512,
        l1b, l2b);
    ProjArgs pa;
    pa.A0[0] = l1b; pa.W0[0] = wb + (0 + i) * WMAT; pa.b0[0] = bq1 + i * 512; pa.o0[0] = q1b;
    pa.A0[1] = t2b; pa.W0[1] = wb + (3 + i) * WMAT; pa.b0[1] = bk1 + i * 512; pa.o0[1] = k1b;
    pa.A0[2] = l2b; pa.W0[2] = wb + (9 + i) * WMAT; pa.b0[2] = bq2 + i * 512; pa.o0[2] = q2b;
    pa.A0[3] = t1b; pa.W0[3] = wb + (12 + i) * WMAT; pa.b0[3] = bk2 + i * 512; pa.o0[3] = k2b;
    pa.scl0[0] = CEXP; pa.scl0[1] = 1.f; pa.scl0[2] = CEXP; pa.scl0[3] = 1.f;
    pa.W2[0] = wb + (6 + i) * WMAT; pa.B2[0] = t2b; pa.b2[0] = bv1 + i * 512; pa.o2[0] = v1b;
    pa.W2[1] = wb + (15 + i) * WMAT; pa.B2[1] = t1b; pa.b2[1] = bv2 + i * 512; pa.o2[1] = v2b;
    proj_kernel<<<1200, 256, 0, stream>>>(pa);
    attn_kernel<<<1600, 128, 0, stream>>>(aa);
  }

  float* out = (float*)d_out;
  head_kernel<<<dim3(13, 4, 8), 256, 0, stream>>>(
      wb + 18 * WMAT, wb + 19 * WMAT, t1b, t2b,
      out1_b, out2_b, bn1_g, bn1_b, bn2_g, bn2_b, out);
}

// Round 19
// 390.575 us; speedup vs baseline: 1.3585x; 1.0478x over previous
//
#include <hip/hip_runtime.h>

typedef __bf16 bf16_t;
typedef __bf16 bf16x8 __attribute__((ext_vector_type(8)));
typedef __bf16 bf16x4 __attribute__((ext_vector_type(4)));
typedef float f32x4 __attribute__((ext_vector_type(4)));
typedef float f32x16 __attribute__((ext_vector_type(16)));
typedef unsigned u32x4 __attribute__((ext_vector_type(4)));

#define NTOK 1568
#define CDIM 512
#define BATCH 4
#define MROWS (BATCH*NTOK)  // 6272
#define RSQ1PEPS 0.9999950000374997f
#define CEXP 0.1803368801111204f    // 0.125 * log2(e), folded into q-projection

__device__ __forceinline__ float fexp2(float x) {
  float r;
  asm("v_exp_f32 %0, %1" : "=v"(r) : "v"(x));
  return r;
}

__device__ __forceinline__ void glds16(const bf16_t* src, bf16_t* dst) {
  __builtin_amdgcn_global_load_lds(
      (const __attribute__((address_space(1))) unsigned*)src,
      (__attribute__((address_space(3))) unsigned*)dst, 16, 0, 0);
}

// ---------------- cast all weights f32 -> bf16 (one launch) ----------------
struct CastArgs { const float* s[20]; };
__global__ __launch_bounds__(256) void cast_kernel(CastArgs ca, bf16_t* __restrict__ out) {
  int idx = blockIdx.x * 256 + threadIdx.x;
  int m = idx >> 16;
  const float4* sp = (const float4*)ca.s[m];
  float4 v = sp[idx & 65535];
  bf16x4 o;
  o[0] = (bf16_t)v.x; o[1] = (bf16_t)v.y; o[2] = (bf16_t)v.z; o[3] = (bf16_t)v.w;
  *(bf16x4*)(out + (size_t)idx * 4) = o;
}

// ---------------- tokenize both inputs: x[b][c][s] -> t[b][s][c] ----------------
struct TokArgs { const float* x[2]; float* tf[2]; bf16_t* tb[2]; };
__global__ __launch_bounds__(256) void tok_kernel(TokArgs ta) {
  __shared__ float tile[32][33];
  int z = blockIdx.z, sel = z >> 2, b = z & 3;
  int c0 = blockIdx.y * 32, s0 = blockIdx.x * 32;
  int tx = threadIdx.x, ty = threadIdx.y;
  const float* xp = ta.x[sel] + (size_t)b * CDIM * NTOK;
  for (int r = 0; r < 32; r += 8)
    tile[ty + r][tx] = xp[(size_t)(c0 + ty + r) * NTOK + s0 + tx];
  __syncthreads();
  float* tfp = ta.tf[sel] + (size_t)b * NTOK * CDIM;
  bf16_t* tbp = ta.tb[sel] + (size_t)b * NTOK * CDIM;
  for (int r = 0; r < 32; r += 8) {
    float v = tile[tx][ty + r];
    size_t idx = (size_t)(s0 + ty + r) * CDIM + c0 + tx;
    tfp[idx] = v;
    tbp[idx] = (bf16_t)v;
  }
}

// ---------------- LayerNorm both streams: f32 in -> bf16 out ----------------
__global__ __launch_bounds__(64) void ln_kernel(
    const float* __restrict__ t1, const float* __restrict__ t2,
    const float* __restrict__ g1, const float* __restrict__ b1,
    const float* __restrict__ g2, const float* __restrict__ b2,
    bf16_t* __restrict__ o1, bf16_t* __restrict__ o2) {
  int row = blockIdx.x;
  const float* t; const float* g; const float* bt; bf16_t* out;
  if (row < MROWS) { t = t1; g = g1; bt = b1; out = o1; }
  else { row -= MROWS; t = t2; g = g2; bt = b2; out = o2; }
  int l = threadIdx.x;
  const float* x = t + (size_t)row * CDIM;
  float4 v0 = ((const float4*)x)[l];
  float4 v1 = ((const float4*)x)[l + 64];
  float s = v0.x + v0.y + v0.z + v0.w + v1.x + v1.y + v1.z + v1.w;
  float sq = v0.x*v0.x + v0.y*v0.y + v0.z*v0.z + v0.w*v0.w
           + v1.x*v1.x + v1.y*v1.y + v1.z*v1.z + v1.w*v1.w;
  for (int m = 1; m < 64; m <<= 1) { s += __shfl_xor(s, m); sq += __shfl_xor(sq, m); }
  float mean = s * (1.f / 512.f);
  float var = sq * (1.f / 512.f) - mean * mean;
  float rs = rsqrtf(var + 1e-5f);
  float4 g0 = ((const float4*)g)[l], g1v = ((const float4*)g)[l + 64];
  float4 b0 = ((const float4*)bt)[l], b1v = ((const float4*)bt)[l + 64];
  bf16x4 o0, o1v;
  o0[0] = (bf16_t)((v0.x - mean) * rs * g0.x + b0.x);
  o0[1] = (bf16_t)((v0.y - mean) * rs * g0.y + b0.y);
  o0[2] = (bf16_t)((v0.z - mean) * rs * g0.z + b0.z);
  o0[3] = (bf16_t)((v0.w - mean) * rs * g0.w + b0.w);
  o1v[0] = (bf16_t)((v1.x - mean) * rs * g1v.x + b1v.x);
  o1v[1] = (bf16_t)((v1.y - mean) * rs * g1v.y + b1v.y);
  o1v[2] = (bf16_t)((v1.z - mean) * rs * g1v.z + b1v.z);
  o1v[3] = (bf16_t)((v1.w - mean) * rs * g1v.w + b1v.w);
  *(bf16x4*)(out + (size_t)row * CDIM + l * 4) = o0;
  *(bf16x4*)(out + (size_t)row * CDIM + 256 + l * 4) = o1v;
}

// ---------------- GEMM core: D = A[M][512] * B[N][512]^T ----------------
// glds16 double-buffered staging (m97 structure): linear [128][32] LDS halves,
// pre-swizzled global source cols, one barrier per K-step.
template<int MODE>
__device__ __forceinline__ void gemm_core(
    bf16_t (* __restrict__ As)[128][32], bf16_t (* __restrict__ Bs)[128][32],
    const bf16_t* __restrict__ A, const bf16_t* __restrict__ Bp,
    const float* __restrict__ bias, const float* __restrict__ bng,
    const float* __restrict__ bnb, bf16_t* __restrict__ outb,
    float* __restrict__ outf, int m0, int n0, int Nvalid, float scl) {
  int tid = threadIdx.x;
  int w = tid >> 6, l = tid & 63, lr = l & 15, kg = l >> 4;
  int wm = (w >> 1) * 64, wn = (w & 1) * 64;
  f32x4 acc[4][4];
  for (int i = 0; i < 4; i++)
    for (int j = 0; j < 4; j++)
      acc[i][j] = f32x4{0.f, 0.f, 0.f, 0.f};

  // staging: wave w fills rows w*16..+15 (issue 0) and +64 (issue 1);
  // lane l -> row base+ (l>>2), 16B slot l&3; source col pre-swizzled by (l>>3)&3
  int srow = w * 16 + (l >> 2);
  int scol = ((l & 3) ^ ((l >> 3) & 3)) << 3;
  const bf16_t* aq0 = A + (size_t)(m0 + srow) * CDIM + scol;
  const bf16_t* aq1 = aq0 + (size_t)64 * CDIM;
  int br0 = n0 + srow, br1 = n0 + srow + 64;
  if (MODE != 0) {
    if (br0 > Nvalid - 1) br0 = Nvalid - 1;
    if (br1 > Nvalid - 1) br1 = Nvalid - 1;
  }
  const bf16_t* bq0 = Bp + (size_t)br0 * CDIM + scol;
  const bf16_t* bq1 = Bp + (size_t)br1 * CDIM + scol;
  int swr = ((lr >> 1) & 3) << 3;   // read swizzle, matches (row>>1)&3 key
  int wq = w * 16;

  // prologue: stage K-step 0 into buffer 0
  glds16(aq0, &As[0][wq][0]);
  glds16(aq1, &As[0][64 + wq][0]);
  glds16(bq0, &Bs[0][wq][0]);
  glds16(bq1, &Bs[0][64 + wq][0]);
  __syncthreads();

  for (int kk = 0; kk < 16; kk++) {
    int bu = kk & 1;
    if (kk < 15) {
      int ko = (kk + 1) * 32;
      glds16(aq0 + ko, &As[bu ^ 1][wq][0]);
      glds16(aq1 + ko, &As[bu ^ 1][64 + wq][0]);
      glds16(bq0 + ko, &Bs[bu ^ 1][wq][0]);
      glds16(bq1 + ko, &Bs[bu ^ 1][64 + wq][0]);
    }
    bf16x8 af[4], bfr[4];
    for (int i = 0; i < 4; i++)
      af[i] = *(const bf16x8*)&As[bu][wm + i * 16 + lr][(kg * 8) ^ swr];
    for (int j = 0; j < 4; j++)
      bfr[j] = *(const bf16x8*)&Bs[bu][wn + j * 16 + lr][(kg * 8) ^ swr];
    for (int i = 0; i < 4; i++)
      for (int j = 0; j < 4; j++)
        acc[i][j] = __builtin_amdgcn_mfma_f32_16x16x32_bf16(af[i], bfr[j], acc[i][j], 0, 0, 0);
    __syncthreads();
  }

  for (int i = 0; i < 4; i++)
    for (int j = 0; j < 4; j++) {
      int rbase = m0 + wm + i * 16 + kg * 4;
      int col = n0 + wn + j * 16 + lr;
      for (int r = 0; r < 4; r++) {
        int row = rbase + r;
        float v = acc[i][j][r];
        if (MODE == 0) {
          v = (v + bias[col]) * scl;
          outb[(size_t)row * CDIM + col] = (bf16_t)v;
        } else if (MODE == 1) {
          v += bias[row];
          v = v > 0.f ? v : 0.f;
          v *= RSQ1PEPS;
          v = v * bng[row] + bnb[row];
          if (col < Nvalid) outf[(size_t)row * NTOK + col] = v;
        } else {
          v += bias[row];
          if (col < Nvalid) outb[(size_t)row * NTOK + col] = (bf16_t)v;
        }
      }
    }
}

// ---------------- fused per-stage projections ----------------
struct ProjArgs {
  const bf16_t* A0[4]; const bf16_t* W0[4]; const float* b0[4]; bf16_t* o0[4];
  float scl0[4];
  const bf16_t* W2[2]; const bf16_t* B2[2]; const float* b2[2]; bf16_t* o2[2];
};
__global__ __launch_bounds__(256) void proj_kernel(ProjArgs p) {
  __shared__ alignas(16) bf16_t As[2][128][32];
  __shared__ alignas(16) bf16_t Bs[2][128][32];
  int id = blockIdx.x;
  if (id < 784) {
    int set = id / 196, rem = id % 196;
    int n0 = (rem & 3) * 128, m0 = (rem >> 2) * 128;
    gemm_core<0>(As, Bs, p.A0[set], p.W0[set], p.b0[set], nullptr, nullptr,
                 p.o0[set], nullptr, m0, n0, 512, p.scl0[set]);
  } else {
    int j = id - 784;
    int unit = j / 52;
    int which = unit >> 2, bat = unit & 3;
    int rem = j % 52;
    int n0 = (rem % 13) * 128, m0 = (rem / 13) * 128;
    gemm_core<2>(As, Bs, p.W2[which], p.B2[which] + (size_t)bat * NTOK * CDIM,
                 p.b2[which], nullptr, nullptr,
                 p.o2[which] + (size_t)bat * CDIM * NTOK, nullptr, m0, n0, NTOK, 1.f);
  }
}

// ---------------- fused out-heads (MODE 1) ----------------
__global__ __launch_bounds__(256) void head_kernel(
    const bf16_t* __restrict__ W1, const bf16_t* __restrict__ W2,
    const bf16_t* __restrict__ t1b, const bf16_t* __restrict__ t2b,
    const float* __restrict__ b1, const float* __restrict__ b2,
    const float* __restrict__ bng1, const float* __restrict__ bnb1,
    const float* __restrict__ bng2, const float* __restrict__ bnb2,
    float* __restrict__ out) {
  __shared__ alignas(16) bf16_t As[2][128][32];
  __shared__ alignas(16) bf16_t Bs[2][128][32];
  int z = blockIdx.z;
  int which = z >> 2, bat = z & 3;
  const bf16_t* A = which ? W2 : W1;
  const bf16_t* Bp = (which ? t2b : t1b) + (size_t)bat * NTOK * CDIM;
  const float* bias = which ? b2 : b1;
  const float* bng = which ? bng2 : bng1;
  const float* bnb = which ? bnb2 : bnb1;
  float* outf = out + (size_t)which * BATCH * CDIM * NTOK + (size_t)bat * CDIM * NTOK;
  int m0 = blockIdx.y * 128, n0 = blockIdx.x * 128;
  gemm_core<1>(As, Bs, A, Bp, bias, bng, bnb, nullptr, outf, m0, n0, NTOK, 1.f);
}

// ---------------- attention helpers ----------------
__device__ __forceinline__ void build_frags(const float* p, bf16x8& Fa, bf16x8& Fb) {
  unsigned pk[8];
#pragma unroll
  for (int g = 0; g < 8; g++) {
    union { bf16_t hh[2]; unsigned u; } cv;
    cv.hh[0] = (bf16_t)p[2 * g];
    cv.hh[1] = (bf16_t)p[2 * g + 1];
    pk[g] = cv.u;
  }
  asm volatile("v_permlane32_swap_b32 %0, %1" : "+v"(pk[0]), "+v"(pk[2]));
  asm volatile("v_permlane32_swap_b32 %0, %1" : "+v"(pk[1]), "+v"(pk[3]));
  asm volatile("v_permlane32_swap_b32 %0, %1" : "+v"(pk[4]), "+v"(pk[6]));
  asm volatile("v_permlane32_swap_b32 %0, %1" : "+v"(pk[5]), "+v"(pk[7]));
  union { u32x4 u; bf16x8 bv; } A, B;
  A.u[0] = pk[0]; A.u[1] = pk[1]; A.u[2] = pk[2]; A.u[3] = pk[3];
  B.u[0] = pk[4]; B.u[1] = pk[5]; B.u[2] = pk[6]; B.u[3] = pk[7];
  Fa = A.bv; Fb = B.bv;
}

// ---------------- fused attention: KVB=32, ring-6, paired steps (R16 best) ----------------
struct AttnArgs {
  const bf16_t* q[2]; const bf16_t* k[2]; const bf16_t* v[2];
  float* tf[2]; bf16_t* tb[2];
};

#define STAGE(TN, SL)                                                         \
  {                                                                           \
    int tnS_ = (TN); if (tnS_ > 48) tnS_ = 48;                                \
    glds16(kgl + (size_t)tnS_ * (32 * CDIM), &Ks[SL][wq8][0]);                \
    glds16(vgl + tnS_ * 32, &Vs[SL][wq16][0]);                                \
  }

#define QK(SL, SA)                                                            \
  {                                                                           \
    const bf16_t* kr_ = &Ks[SL][lo][0];                                       \
    __builtin_amdgcn_s_setprio(1);                                            \
    SA = __builtin_amdgcn_mfma_f32_32x32x16_bf16(                             \
        *(const bf16x8*)(kr_ + ((hi * 8) ^ sw3)), qf[0], z, 0, 0, 0);         \
    SA = __builtin_amdgcn_mfma_f32_32x32x16_bf16(                             \
        *(const bf16x8*)(kr_ + ((16 + hi * 8) ^ sw3)), qf[1], SA, 0, 0, 0);   \
    SA = __builtin_amdgcn_mfma_f32_32x32x16_bf16(                             \
        *(const bf16x8*)(kr_ + ((32 + hi * 8) ^ sw3)), qf[2], SA, 0, 0, 0);   \
    SA = __builtin_amdgcn_mfma_f32_32x32x16_bf16(                             \
        *(const bf16x8*)(kr_ + ((48 + hi * 8) ^ sw3)), qf[3], SA, 0, 0, 0);   \
    __builtin_amdgcn_s_setprio(0);                                            \
  }

#define FIN(SA, SL)                                                           \
  {                                                                           \
    float pa_[16];                                                            \
    _Pragma("unroll")                                                         \
    for (int r_ = 0; r_ < 16; r_++) pa_[r_] = fexp2(SA[r_]);                  \
    bf16x8 F0_, F1_;                                                          \
    build_frags(pa_, F0_, F1_);                                               \
    __builtin_amdgcn_s_setprio(1);                                            \
    ls = __builtin_amdgcn_mfma_f32_32x32x16_bf16(kone, F0_, ls, 0, 0, 0);     \
    ls = __builtin_amdgcn_mfma_f32_32x32x16_bf16(kone, F1_, ls, 0, 0, 0);     \
    ot0 = __builtin_amdgcn_mfma_f32_32x32x16_bf16(                            \
        *(const bf16x8*)(&Vs[SL][lo][(hi * 8) ^ sw2]), F0_, ot0, 0, 0, 0);    \
    ot0 = __builtin_amdgcn_mfma_f32_32x32x16_bf16(                            \
        *(const bf16x8*)(&Vs[SL][lo][(16 + hi * 8) ^ sw2]), F1_, ot0, 0, 0, 0);\
    ot1 = __builtin_amdgcn_mfma_f32_32x32x16_bf16(                            \
        *(const bf16x8*)(&Vs[SL][32 + lo][(hi * 8) ^ sw2]), F0_, ot1, 0, 0, 0);\
    ot1 = __builtin_amdgcn_mfma_f32_32x32x16_bf16(                            \
        *(const bf16x8*)(&Vs[SL][32 + lo][(16 + hi * 8) ^ sw2]), F1_, ot1, 0, 0, 0);\
    __builtin_amdgcn_s_setprio(0);                                            \
  }

// one PAIR: two tiles per barrier (ring-6, WAR diffs {2..5} safe);
// vmcnt(2) retires through stage(T+4), leaves stage(T+5) in flight.
#define PAIR(T, S0_, S1_, S2_, SS1, SS2)                                      \
  {                                                                           \
    STAGE((T) + 4, SS1);                                                      \
    STAGE((T) + 5, SS2);                                                      \
    QK(S1_, saB);                                                             \
    FIN(saA, S0_);                                                            \
    QK(S2_, saA);                                                             \
    FIN(saB, S1_);                                                            \
    asm volatile("s_waitcnt vmcnt(2)" ::: "memory");                          \
    __builtin_amdgcn_s_barrier();                                             \
  }

__global__ __launch_bounds__(256) void attn_kernel(AttnArgs aa) {
  __shared__ alignas(16) bf16_t Ks[6][32][64];   // 24KB, 3-bit XOR swizzle
  __shared__ alignas(16) bf16_t Vs[6][64][32];   // 24KB, V^T, 2-bit XOR swizzle
  int id = blockIdx.x;
  int xcd = id & 7, sl = id >> 3;          // sl in 0..103
  int g = xcd + ((sl / 13) << 3);          // group 0..63
  int qt = sl % 13;
  int ss = g >> 5, b = (g >> 3) & 3, h = g & 7;
  const bf16_t* qg = aa.q[ss];
  const bf16_t* kgp = aa.k[ss];
  const bf16_t* vtg = aa.v[ss];
  float* tf = aa.tf[ss];
  bf16_t* tb = aa.tb[ss];
  int tid = threadIdx.x, w = tid >> 6, l = tid & 63;
  int lo = l & 31, hi = l >> 5;
  int wq8 = w * 8, wq16 = w * 16;
  int sw3 = (lo & 7) << 3;
  int sw2 = ((lo >> 1) & 3) << 3;
  const size_t kbase = ((size_t)b * NTOK) * CDIM + h * 64;
  const size_t vbase = ((size_t)b * CDIM + h * 64) * NTOK;

  int q0 = qt * 128 + w * 32;
  int qrow = q0 + lo;
  int qr = qrow < NTOK ? qrow : NTOK - 1;
  const bf16_t* qp = qg + kbase + (size_t)qr * CDIM + hi * 8;
  bf16x8 qf[4];
  qf[0] = *(const bf16x8*)(qp);
  qf[1] = *(const bf16x8*)(qp + 16);
  qf[2] = *(const bf16x8*)(qp + 32);
  qf[3] = *(const bf16x8*)(qp + 48);
  asm volatile("" : "+v"(qf[0]), "+v"(qf[1]), "+v"(qf[2]), "+v"(qf[3]));
  asm volatile("s_waitcnt vmcnt(0)" ::: "memory");   // drain Q so vmcnt counting is exact

  const bf16_t* kgl = kgp + kbase + (size_t)(wq8 + (l >> 3)) * CDIM
                      + (((l & 7) ^ ((l >> 3) & 7)) << 3);
  const bf16_t* vgl = vtg + vbase + (size_t)(wq16 + (l >> 2)) * NTOK
                      + (((l & 3) ^ ((l >> 3) & 3)) << 3);

  bf16x8 kone;
#pragma unroll
  for (int j = 0; j < 8; j++) kone[j] = (bf16_t)1.0f;

  f32x16 ot0, ot1, ls, z, saA, saB;
#pragma unroll
  for (int r = 0; r < 16; r++) { ot0[r] = 0.f; ot1[r] = 0.f; ls[r] = 0.f; z[r] = 0.f; }

  // prologue: stage tiles 0..3; retire 0,1,2 (tile-3 loads stay in flight)
  STAGE(0, 0);
  STAGE(1, 1);
  STAGE(2, 2);
  STAGE(3, 3);
  asm volatile("s_waitcnt vmcnt(2)" ::: "memory");
  __builtin_amdgcn_s_barrier();
  QK(0, saA);

  // steady loop: 24 pairs = tiles 0..47
  for (int t = 0; t <= 42; t += 6) {
    PAIR(t + 0, 0, 1, 2, 4, 5);
    PAIR(t + 2, 2, 3, 4, 0, 1);
    PAIR(t + 4, 4, 5, 0, 2, 3);
  }
  // tail: tile 48 (slot 0); its QK was the last pair's second QK -> saA
  FIN(saA, 0);
  asm volatile("s_waitcnt vmcnt(0)" ::: "memory");   // drain clamped dup stages

  if (qrow < NTOK) {
    float inv = 1.f / ls[0];
    float* tfp = tf + ((size_t)b * NTOK + qrow) * CDIM + h * 64 + hi * 4;
    bf16_t* tbp = tb + ((size_t)b * NTOK + qrow) * CDIM + h * 64 + hi * 4;
#pragma unroll
    for (int db = 0; db < 2; db++) {
#pragma unroll
      for (int gq = 0; gq < 4; gq++) {
        int doff = db * 32 + gq * 8;
        float4 old = *(float4*)(tfp + doff);
        float4 nv;
        float a0 = (db ? ot1[gq * 4 + 0] : ot0[gq * 4 + 0]) * inv;
        float a1 = (db ? ot1[gq * 4 + 1] : ot0[gq * 4 + 1]) * inv;
        float a2 = (db ? ot1[gq * 4 + 2] : ot0[gq * 4 + 2]) * inv;
        float a3 = (db ? ot1[gq * 4 + 3] : ot0[gq * 4 + 3]) * inv;
        nv.x = old.x + a0; nv.y = old.y + a1; nv.z = old.z + a2; nv.w = old.w + a3;
        *(float4*)(tfp + doff) = nv;
        bf16x4 ob;
        ob[0] = (bf16_t)nv.x; ob[1] = (bf16_t)nv.y;
        ob[2] = (bf16_t)nv.z; ob[3] = (bf16_t)nv.w;
        *(bf16x4*)(tbp + doff) = ob;
      }
    }
  }
}

extern "C" void kernel_launch(void* const* d_in, const int* in_sizes, int n_in,
                              void* d_out, int out_size, void* d_ws, size_t ws_size,
                              hipStream_t stream) {
  (void)in_sizes; (void)n_in; (void)out_size; (void)ws_size;
  const float* x1 = (const float*)d_in[0];
  const float* x2 = (const float*)d_in[1];
  const float* Wq1 = (const float*)d_in[2];
  const float* bq1 = (const float*)d_in[3];
  const float* Wk1 = (const float*)d_in[4];
  const float* bk1 = (const float*)d_in[5];
  const float* Wv1 = (const float*)d_in[6];
  const float* bv1 = (const float*)d_in[7];
  const float* ln1_g = (const float*)d_in[8];
  const float* ln1_b = (const float*)d_in[9];
  const float* Wq2 = (const float*)d_in[10];
  const float* bq2 = (const float*)d_in[11];
  const float* Wk2 = (const float*)d_in[12];
  const float* bk2 = (const float*)d_in[13];
  const float* Wv2 = (const float*)d_in[14];
  const float* bv2 = (const float*)d_in[15];
  const float* ln2_g = (const float*)d_in[16];
  const float* ln2_b = (const float*)d_in[17];
  const float* out1_w = (const float*)d_in[18];
  const float* out1_b = (const float*)d_in[19];
  const float* bn1_g = (const float*)d_in[20];
  const float* bn1_b = (const float*)d_in[21];
  const float* out2_w = (const float*)d_in[22];
  const float* out2_b = (const float*)d_in[23];
  const float* bn2_g = (const float*)d_in[24];
  const float* bn2_b = (const float*)d_in[25];

  const size_t WMAT = 512 * 512;
  char* ws = (char*)d_ws;
  bf16_t* wb = (bf16_t*)ws;
  size_t off = 20 * WMAT * sizeof(bf16_t);
  float* t1f = (float*)(ws + off); off += (size_t)MROWS * CDIM * 4;
  float* t2f = (float*)(ws + off); off += (size_t)MROWS * CDIM * 4;
  bf16_t* t1b = (bf16_t*)(ws + off); off += (size_t)MROWS * CDIM * 2;
  bf16_t* t2b = (bf16_t*)(ws + off); off += (size_t)MROWS * CDIM * 2;
  bf16_t* l1b = (bf16_t*)(ws + off); off += (size_t)MROWS * CDIM * 2;
  bf16_t* l2b = (bf16_t*)(ws + off); off += (size_t)MROWS * CDIM * 2;
  bf16_t* q1b = (bf16_t*)(ws + off); off += (size_t)MROWS * CDIM * 2;
  bf16_t* k1b = (bf16_t*)(ws + off); off += (size_t)MROWS * CDIM * 2;
  bf16_t* v1b = (bf16_t*)(ws + off); off += (size_t)MROWS * CDIM * 2;  // V^T [b][512][1568]
  bf16_t* q2b = (bf16_t*)(ws + off); off += (size_t)MROWS * CDIM * 2;
  bf16_t* k2b = (bf16_t*)(ws + off); off += (size_t)MROWS * CDIM * 2;
  bf16_t* v2b = (bf16_t*)(ws + off); off += (size_t)MROWS * CDIM * 2;  // V^T

  CastArgs ca;
  for (int i = 0; i < 3; i++) {
    ca.s[0 + i] = Wq1 + (size_t)i * WMAT;
    ca.s[3 + i] = Wk1 + (size_t)i * WMAT;
    ca.s[6 + i] = Wv1 + (size_t)i * WMAT;
    ca.s[9 + i] = Wq2 + (size_t)i * WMAT;
    ca.s[12 + i] = Wk2 + (size_t)i * WMAT;
    ca.s[15 + i] = Wv2 + (size_t)i * WMAT;
  }
  ca.s[18] = out1_w;
  ca.s[19] = out2_w;
  cast_kernel<<<5120, 256, 0, stream>>>(ca, wb);

  TokArgs ta;
  ta.x[0] = x1; ta.x[1] = x2;
  ta.tf[0] = t1f; ta.tf[1] = t2f;
  ta.tb[0] = t1b; ta.tb[1] = t2b;
  tok_kernel<<<dim3(49, 16, 8), dim3(32, 8), 0, stream>>>(ta);

  AttnArgs aa;
  aa.q[0] = q1b; aa.q[1] = q2b;
  aa.k[0] = k1b; aa.k[1] = k2b;
  aa.v[0] = v1b; aa.v[1] = v2b;
  aa.tf[0] = t1f; aa.tf[1] = t2f;
  aa.tb[0] = t1b; aa.tb[1] = t2b;

  for (int i = 0; i < 3; i++) {
    ln_kernel<<<2 * MROWS, 64, 0, stream>>>(t1f, t2f,
        ln1_g + i * 512, ln1_b + i * 512, ln2_g + i * 512, ln2_b + i * 512,
        l1b, l2b);
    ProjArgs pa;
    pa.A0[0] = l1b; pa.W0[0] = wb + (0 + i) * WMAT; pa.b0[0] = bq1 + i * 512; pa.o0[0] = q1b;
    pa.A0[1] = t2b; pa.W0[1] = wb + (3 + i) * WMAT; pa.b0[1] = bk1 + i * 512; pa.o0[1] = k1b;
    pa.A0[2] = l2b; pa.W0[2] = wb + (9 + i) * WMAT; pa.b0[2] = bq2 + i * 512; pa.o0[2] = q2b;
    pa.A0[3] = t1b; pa.W0[3] = wb + (12 + i) * WMAT; pa.b0[3] = bk2 + i * 512; pa.o0[3] = k2b;
    pa.scl0[0] = CEXP; pa.scl0[1] = 1.f; pa.scl0[2] = CEXP; pa.scl0[3] = 1.f;
    pa.W2[0] = wb + (6 + i) * WMAT; pa.B2[0] = t2b; pa.b2[0] = bv1 + i * 512; pa.o2[0] = v1b;
    pa.W2[1] = wb + (15 + i) * WMAT; pa.B2[1] = t1b; pa.b2[1] = bv2 + i * 512; pa.o2[1] = v2b;
    proj_kernel<<<1200, 256, 0, stream>>>(pa);
    attn_kernel<<<832, 256, 0, stream>>>(aa);
  }

  float* out = (float*)d_out;
  head_kernel<<<dim3(13, 4, 8), 256, 0, stream>>>(
      wb + 18 * WMAT, wb + 19 * WMAT, t1b, t2b,
      out1_b, out2_b, bn1_g, bn1_b, bn2_g, bn2_b, out);
}